// Round 5
// baseline (179.624 us; speedup 1.0000x reference)
//
#include <hip/hip_runtime.h>
#include <hip/hip_bf16.h>

// DilateAttention: B=4, d=384 (12 heads x 32), H=W=64, 3x3 taps, dilation 2, pad 2.
// f32 in / f32 out. Round 5: split channels across 4 threads/pixel to 4x the
// wave count (12288 waves vs 3072). Partial logits reduced through LDS;
// softmax recomputed per group (cheap); each group owns 8 output channels.

#define HD   32
#define NHD  12
#define DDIM 384
#define HH   64
#define WW   64
#define HWSZ 4096
#define SCALEF 0.17677669529663687f  // 1/sqrt(32)

// block = 256: 64 x-lanes * 4 channel-groups, one (b, head, y-row) per block.
// grid = B*NH*H = 4*12*64 = 3072.
__global__ __launch_bounds__(256, 6) void dilate_attn(const float* __restrict__ q,
                                                      const float* __restrict__ k,
                                                      const float* __restrict__ v,
                                                      float* __restrict__ out) {
    const int tid = threadIdx.x;
    const int x   = tid & 63;
    const int g   = tid >> 6;          // channel group 0..3 (8 ch each)
    const int bz  = blockIdx.x;
    const int bh  = bz >> 6;           // b*NH + n
    const int b   = bh / NHD;
    const int n   = bh - b * NHD;
    const int y   = bz & 63;

    const size_t chan_base = (size_t)(b * DDIM + n * HD) * HWSZ;
    const int pix = y * WW + x;

    // 9 tap offsets, clamped to center when OOB (loads always legal); validity kept.
    int  toff[9];
    bool tval[9];
#pragma unroll
    for (int di = 0; di < 3; ++di) {
        int yy = y + 2 * di - 2;
        bool vy = (yy >= 0) && (yy < HH);
#pragma unroll
        for (int p = 0; p < 3; ++p) {
            int xo = x + 2 * p - 2;
            bool ok = vy && (xo >= 0) && (xo < WW);
            tval[di * 3 + p] = ok;
            toff[di * 3 + p] = ok ? (yy * WW + xo) : pix;
        }
    }

    // ---------------- Phase 1: partial logits over this group's 8 channels ----------------
    const size_t goff = (size_t)(g * 8) * HWSZ;
    const float* qb = q + chan_base + goff + pix;
    float qreg[8];
#pragma unroll
    for (int c = 0; c < 8; ++c) qreg[c] = qb[(size_t)c * HWSZ];

    __shared__ float part[36 * 64];    // [tap*4 + group][x]; stride-1 in x -> no conflicts
    const float* kb = k + chan_base + goff;
#pragma unroll
    for (int t = 0; t < 9; ++t) {
        const float* kt = kb + toff[t];
        float a0 = 0.f, a1 = 0.f;
#pragma unroll
        for (int c = 0; c < 8; c += 2) {
            a0 += qreg[c]     * kt[(size_t)c * HWSZ];
            a1 += qreg[c + 1] * kt[(size_t)(c + 1) * HWSZ];
        }
        part[(t * 4 + g) * 64 + x] = a0 + a1;
    }
    __syncthreads();

    // ---------------- Reduce partials + softmax over 9 (redundant per group) ----------------
    float l[9];
#pragma unroll
    for (int t = 0; t < 9; ++t) {
        float s = part[(t * 4 + 0) * 64 + x] + part[(t * 4 + 1) * 64 + x]
                + part[(t * 4 + 2) * 64 + x] + part[(t * 4 + 3) * 64 + x];
        l[t] = tval[t] ? (s * SCALEF) : 0.f;   // zero-pad taps: logit exactly 0
    }
    float m = l[0];
#pragma unroll
    for (int t = 1; t < 9; ++t) m = fmaxf(m, l[t]);
    float w[9], s = 0.f;
#pragma unroll
    for (int t = 0; t < 9; ++t) { w[t] = __expf(l[t] - m); s += w[t]; }
    float inv = 1.0f / s;
#pragma unroll
    for (int t = 0; t < 9; ++t) w[t] = tval[t] ? (w[t] * inv) : 0.f;  // padded V == 0

    // ---------------- Phase 2: weighted V over this group's 8 channels ----------------
    const float* vb = v + chan_base + goff;
    float o[8];
#pragma unroll
    for (int c = 0; c < 8; ++c) o[c] = 0.f;
#pragma unroll
    for (int t = 0; t < 9; ++t) {
        const float* vt = vb + toff[t];
        float wt = w[t];
#pragma unroll
        for (int c = 0; c < 8; ++c) o[c] += wt * vt[(size_t)c * HWSZ];
    }

    // out[b, y, x, n*32 + g*8 .. +7]; element offset multiple of 8 -> 16-B aligned
    float* ob = out + ((size_t)(b * HWSZ) + pix) * DDIM + n * HD + g * 8;
    *(float4*)(ob)     = make_float4(o[0], o[1], o[2], o[3]);
    *(float4*)(ob + 4) = make_float4(o[4], o[5], o[6], o[7]);
}

extern "C" void kernel_launch(void* const* d_in, const int* in_sizes, int n_in,
                              void* d_out, int out_size, void* d_ws, size_t ws_size,
                              hipStream_t stream) {
    const float* q = (const float*)d_in[0];
    const float* k = (const float*)d_in[1];
    const float* v = (const float*)d_in[2];
    float* out = (float*)d_out;
    // grid = B * NH * H = 3072 blocks, 256 threads
    hipLaunchKernelGGL(dilate_attn, dim3(3072), dim3(256), 0, stream, q, k, v, out);
}

// Round 6
// 168.816 us; speedup vs baseline: 1.0640x; 1.0640x over previous
//
#include <hip/hip_runtime.h>
#include <hip/hip_bf16.h>

// DilateAttention: B=4, d=384 (12 heads x 32), H=W=64, 3x3 taps, dilation 2, pad 2.
// f32 in / f32 out. Round 6 = Round 5 parallelism (12288 waves, 1px x 8ch/thread)
// + full-line coalesced writes via LDS restage + XCD y-band swizzle for tap reuse.

#define HD   32
#define NHD  12
#define DDIM 384
#define HH   64
#define WW   64
#define HWSZ 4096
#define SCALEF 0.17677669529663687f  // 1/sqrt(32)

// block = 256: 64 x-lanes * 4 channel-groups (8 ch each). One (b, head, y) row per block.
// grid = B*NH*H = 3072. blockIdx decode puts an 8-row y-band on one XCD (z%8 round-robin).
__global__ __launch_bounds__(256, 6) void dilate_attn(const float* __restrict__ q,
                                                      const float* __restrict__ k,
                                                      const float* __restrict__ v,
                                                      float* __restrict__ out) {
    const int tid = threadIdx.x;
    const int x   = tid & 63;
    const int g   = tid >> 6;          // channel group 0..3

    // swizzle: yg = XCD slot (z%8), r sweeps fast within band -> tap rows (y, y±2)
    // are touched by dispatch-adjacent blocks on the SAME XCD.
    const int z   = blockIdx.x;
    const int yg  = z & 7;
    const int G2  = z >> 3;            // bh*8 + r
    const int r   = G2 & 7;
    const int bh  = G2 >> 3;           // b*NH + n
    const int b   = bh / NHD;
    const int n   = bh - b * NHD;
    const int y   = yg * 8 + r;

    const size_t chan_base = (size_t)(b * DDIM + n * HD) * HWSZ;
    const int pix = y * WW + x;

    // 9 tap offsets, clamped to center when OOB (loads always legal); validity kept.
    int  toff[9];
    bool tval[9];
#pragma unroll
    for (int di = 0; di < 3; ++di) {
        int yy = y + 2 * di - 2;
        bool vy = (yy >= 0) && (yy < HH);
#pragma unroll
        for (int p = 0; p < 3; ++p) {
            int xo = x + 2 * p - 2;
            bool ok = vy && (xo >= 0) && (xo < WW);
            tval[di * 3 + p] = ok;
            toff[di * 3 + p] = ok ? (yy * WW + xo) : pix;
        }
    }

    __shared__ float part[36 * 64];     // [tap*4 + g][x] partial logits
    __shared__ float ostage[64 * 36];   // [x][36] (stride 36: b128-aligned, bank-spread)

    // ---------------- Phase 1: partial logits over this group's 8 channels ----------------
    const size_t goff = (size_t)(g * 8) * HWSZ;
    const float* qb = q + chan_base + goff + pix;
    float qreg[8];
#pragma unroll
    for (int c = 0; c < 8; ++c) qreg[c] = qb[(size_t)c * HWSZ];

    const float* kb = k + chan_base + goff;
#pragma unroll
    for (int t = 0; t < 9; ++t) {
        const float* kt = kb + toff[t];
        float a0 = 0.f, a1 = 0.f;
#pragma unroll
        for (int c = 0; c < 8; c += 2) {
            a0 += qreg[c]     * kt[(size_t)c * HWSZ];
            a1 += qreg[c + 1] * kt[(size_t)(c + 1) * HWSZ];
        }
        part[(t * 4 + g) * 64 + x] = a0 + a1;
    }
    __syncthreads();

    // ---------------- Reduce partials + softmax over 9 (redundant per group) ----------------
    float l[9];
#pragma unroll
    for (int t = 0; t < 9; ++t) {
        float s = part[(t * 4 + 0) * 64 + x] + part[(t * 4 + 1) * 64 + x]
                + part[(t * 4 + 2) * 64 + x] + part[(t * 4 + 3) * 64 + x];
        l[t] = tval[t] ? (s * SCALEF) : 0.f;   // zero-pad taps: logit exactly 0
    }
    float m = l[0];
#pragma unroll
    for (int t = 1; t < 9; ++t) m = fmaxf(m, l[t]);
    float w[9], s = 0.f;
#pragma unroll
    for (int t = 0; t < 9; ++t) { w[t] = __expf(l[t] - m); s += w[t]; }
    float inv = 1.0f / s;
#pragma unroll
    for (int t = 0; t < 9; ++t) w[t] = tval[t] ? (w[t] * inv) : 0.f;  // padded V == 0

    // ---------------- Phase 2: weighted V over this group's 8 channels ----------------
    const float* vb = v + chan_base + goff;
    float o[8];
#pragma unroll
    for (int c = 0; c < 8; ++c) o[c] = 0.f;
#pragma unroll
    for (int t = 0; t < 9; ++t) {
        const float* vt = vb + toff[t];
        float wt = w[t];
#pragma unroll
        for (int c = 0; c < 8; ++c) o[c] += wt * vt[(size_t)c * HWSZ];
    }

    // ---------------- Restage through LDS; one wave writes full 128-B lines ----------------
    float* op = ostage + x * 36 + g * 8;         // element offset multiple of 4 -> b128 ok
    *(float4*)(op)     = make_float4(o[0], o[1], o[2], o[3]);
    *(float4*)(op + 4) = make_float4(o[4], o[5], o[6], o[7]);
    __syncthreads();

    // copy-out: 512 float4 chunks (64 px * 8), 2 per thread; 8 consecutive lanes
    // cover one pixel's 128 contiguous bytes at out[b,y,po, n*32 .. n*32+31].
    float* outrow = out + ((size_t)(b * HH + y) * WW) * DDIM + n * HD;
#pragma unroll
    for (int sIt = 0; sIt < 2; ++sIt) {
        int flat = sIt * 256 + tid;
        int po = flat >> 3;
        int ch = (flat & 7) * 4;
        float4 val = *(const float4*)(ostage + po * 36 + ch);
        *(float4*)(outrow + (size_t)po * DDIM + ch) = val;
    }
}

extern "C" void kernel_launch(void* const* d_in, const int* in_sizes, int n_in,
                              void* d_out, int out_size, void* d_ws, size_t ws_size,
                              hipStream_t stream) {
    const float* q = (const float*)d_in[0];
    const float* k = (const float*)d_in[1];
    const float* v = (const float*)d_in[2];
    float* out = (float*)d_out;
    // grid = B * NH * H = 3072 blocks, 256 threads
    hipLaunchKernelGGL(dilate_attn, dim3(3072), dim3(256), 0, stream, q, k, v, out);
}

// Round 7
// 151.895 us; speedup vs baseline: 1.1826x; 1.1114x over previous
//
#include <hip/hip_runtime.h>

// DilateAttention: B=4, d=384 (12 heads x 32), H=W=64, 3x3 taps, dilation 2, pad 2.
// f32 in / f32 out. Round 7: coalesced float4 staging of k/v rows into LDS
// (shared buffer, staged k then v), register-prefetched v/q, LDS tap gathers.
// Grid decode: heads n,n+1 adjacent on same XCD slot (write-line merge);
// y-bands per XCD (tap-row L2 reuse).

#define HD   32
#define NHD  12
#define DDIM 384
#define HH   64
#define WW   64
#define HWSZ 4096
#define SCALEF 0.17677669529663687f  // 1/sqrt(32)
#define XPAD 72                      // padded x extent: [0..3]=0, data 4..67, [68..71]=0

// block = 256: 64 x-lanes * 4 channel-groups (8 ch each). grid = B*NH*H = 3072.
__global__ __launch_bounds__(256) void dilate_attn(const float* __restrict__ q,
                                                   const float* __restrict__ k,
                                                   const float* __restrict__ v,
                                                   float* __restrict__ out) {
    __shared__ float kv[3 * 32 * XPAD];   // 27648 B: [row][ch][XPAD], holds k then v
    __shared__ float part[36 * 64];       // 9216 B: QK partials; reused as out-stage

    const int tid = threadIdx.x;
    const int x   = tid & 63;
    const int g   = tid >> 6;             // channel group (== wave id)

    // z = xcd + 8*(n + 12*(r + 8*b)); y = xcd*8 + r.
    // -> heads n,n+1 of same (b,y): dz=8 (same XCD, adjacent dispatch);
    //    rows y,y+2 same head: dz=192 (same XCD band).
    const int z   = blockIdx.x;
    const int xcd = z & 7;
    const int s   = z >> 3;
    const int n   = s % NHD;
    const int s2  = s / NHD;
    const int r   = s2 & 7;
    const int b   = s2 >> 3;
    const int y   = xcd * 8 + r;

    const size_t chan_base = (size_t)(b * DDIM + n * HD) * HWSZ;

    // ---------- staging decode: 6 float4 per thread per tensor ----------
    int    slds[6];
    size_t sgl[6];
    bool   sok[6];
#pragma unroll
    for (int i = 0; i < 6; ++i) {
        int vid = tid + (i << 8);          // 0..1535
        int row = vid >> 9;                // 0..2
        int rem = vid & 511;
        int ch  = rem >> 4;                // 0..31
        int seg = rem & 15;                // 0..15 (x4 segment)
        int yy  = y + 2 * row - 2;
        sok[i]  = (yy >= 0) && (yy < HH);
        sgl[i]  = (size_t)ch * HWSZ + (size_t)(sok[i] ? yy : 0) * WW + seg * 4;
        slds[i] = (row * 32 + ch) * XPAD + 4 + seg * 4;
    }

    const float* kb = k + chan_base;
    const float* vb = v + chan_base;
    const float* qb = q + chan_base + y * WW + x;

    // ---------- prefetch: k stage, v stage (held in regs), q ----------
    const float4 fz = make_float4(0.f, 0.f, 0.f, 0.f);
    float4 kreg[6], vreg[6];
#pragma unroll
    for (int i = 0; i < 6; ++i) kreg[i] = sok[i] ? *(const float4*)(kb + sgl[i]) : fz;
#pragma unroll
    for (int i = 0; i < 6; ++i) vreg[i] = sok[i] ? *(const float4*)(vb + sgl[i]) : fz;
    float qreg[8];
#pragma unroll
    for (int c = 0; c < 8; ++c) qreg[c] = qb[(size_t)(g * 8 + c) * HWSZ];

    // zero x-pads (stay zero for both k and v phases)
#pragma unroll
    for (int it = 0; it < 3; ++it) {
        int idx = tid + it * 256;          // 0..767 = 3 rows * 32 ch * 8 pad slots
        int row = idx >> 8;
        int rem = idx & 255;
        int ch  = rem >> 3;
        int j   = rem & 7;
        int xx  = (j < 4) ? j : (64 + j);  // 0..3 / 68..71
        kv[(row * 32 + ch) * XPAD + xx] = 0.f;
    }

#pragma unroll
    for (int i = 0; i < 6; ++i) *(float4*)(&kv[slds[i]]) = kreg[i];
    __syncthreads();                       // B1: k staged

    // ---------- QK partials (8 ch per group) ----------
#pragma unroll
    for (int t = 0; t < 9; ++t) {
        int row = t / 3, p = t % 3;
        int xx = x + 2 + 2 * p;            // in [2, 69]; pads give exact 0
        const float* kp = &kv[(row * 32 + g * 8) * XPAD + xx];
        float a0 = 0.f, a1 = 0.f;
#pragma unroll
        for (int c = 0; c < 8; c += 2) {
            a0 += qreg[c]     * kp[(size_t)c * XPAD];
            a1 += qreg[c + 1] * kp[(size_t)(c + 1) * XPAD];
        }
        part[(t * 4 + g) * 64 + x] = a0 + a1;
    }
    __syncthreads();                       // B2: partials visible

    // ---------- reduce + softmax over 9 (redundant per group) ----------
    float l[9];
#pragma unroll
    for (int t = 0; t < 9; ++t) {
        l[t] = (part[(t * 4 + 0) * 64 + x] + part[(t * 4 + 1) * 64 + x]
              + part[(t * 4 + 2) * 64 + x] + part[(t * 4 + 3) * 64 + x]) * SCALEF;
    }
    float m = l[0];
#pragma unroll
    for (int t = 1; t < 9; ++t) m = fmaxf(m, l[t]);
    float w[9], sm = 0.f;
#pragma unroll
    for (int t = 0; t < 9; ++t) { w[t] = __expf(l[t] - m); sm += w[t]; }
    float inv = 1.0f / sm;
#pragma unroll
    for (int t = 0; t < 9; ++t) w[t] *= inv;   // OOB taps: v staged 0 -> no contribution

    __syncthreads();                       // B3: part + kv reads done
#pragma unroll
    for (int i = 0; i < 6; ++i) *(float4*)(&kv[slds[i]]) = vreg[i];
    __syncthreads();                       // B4: v staged

    // ---------- PV (8 ch per group) ----------
    float o[8];
#pragma unroll
    for (int c = 0; c < 8; ++c) o[c] = 0.f;
#pragma unroll
    for (int t = 0; t < 9; ++t) {
        int row = t / 3, p = t % 3;
        int xx = x + 2 + 2 * p;
        const float* vp = &kv[(row * 32 + g * 8) * XPAD + xx];
        float wt = w[t];
#pragma unroll
        for (int c = 0; c < 8; ++c) o[c] += wt * vp[(size_t)c * XPAD];
    }

    // ---------- stage output in part-buffer; coalesced full-line copy-out ----------
    float* ost = part;                     // 64 px * 36 stride (2304 floats = fits)
    *(float4*)(&ost[x * 36 + g * 8])     = make_float4(o[0], o[1], o[2], o[3]);
    *(float4*)(&ost[x * 36 + g * 8 + 4]) = make_float4(o[4], o[5], o[6], o[7]);
    __syncthreads();                       // B5

    float* outrow = out + ((size_t)(b * HH + y) * WW) * DDIM + n * HD;
#pragma unroll
    for (int sIt = 0; sIt < 2; ++sIt) {
        int flat = sIt * 256 + tid;
        int po  = flat >> 3;               // pixel 0..63
        int ch4 = (flat & 7) * 4;          // 0,4,...,28
        float4 val = *(const float4*)(&ost[po * 36 + ch4]);
        *(float4*)(outrow + (size_t)po * DDIM + ch4) = val;  // 8 lanes = one 128B chunk
    }
}

extern "C" void kernel_launch(void* const* d_in, const int* in_sizes, int n_in,
                              void* d_out, int out_size, void* d_ws, size_t ws_size,
                              hipStream_t stream) {
    const float* q = (const float*)d_in[0];
    const float* k = (const float*)d_in[1];
    const float* v = (const float*)d_in[2];
    float* out = (float*)d_out;
    // grid = B * NH * H = 3072 blocks, 256 threads
    hipLaunchKernelGGL(dilate_attn, dim3(3072), dim3(256), 0, stream, q, k, v, out);
}